// Round 4
// baseline (749.152 us; speedup 1.0000x reference)
//
#include <hip/hip_runtime.h>
#include <hip/hip_bf16.h>
#include <stdint.h>

// ---- problem constants ----
#define B_ATOMS 8192
#define C_CH    128
#define L_DIM   16
#define E_EL    10
#define NK3     23
#define NK2     4
#define NTRI    136   // 16*17/2 upper-triangle pairs
#define KPAD    160   // K padded to 32-multiple for 16x16x32 MFMA
#define NCOL    384   // 368 (i*23+k3) + 4 (k2) + 1 (U1 col 372) + 11 pad
#define KSB     336   // XX LDS k-stride BYTES (168 bf16; 84 dwords = 20 mod 32 -> <=2-way b128)
#define XTS     132   // XT f32 row stride
#define WTS     132   // wtab f32 row stride

// ---- LDS layout (bytes) ----
#define XX_OFF  0          // 128*336               = 43008
#define XB_OFF  43008      // bf16 [c][16]          =  4096 -> 47104
#define XT_OFF  47104      // f32 [16][132]         =  8448 -> 55552
#define WT_OFF  55552      // f32 [39][132]         = 20592 -> 76144
#define WS_OFF  76144      // f32 [4][128]          =  2048 -> 78192
#define SMEM_BYTES 78192   // x2 = 156384 <= 163840 -> 2 blocks/CU

typedef __attribute__((ext_vector_type(8))) short short8;
typedef __attribute__((ext_vector_type(4))) float f32x4;

struct TriLut { unsigned char p[NTRI]; unsigned char q[NTRI]; };
static constexpr TriLut make_lut() {
  TriLut t{};
  int idx = 0;
  for (int p = 0; p < 16; ++p)
    for (int q = p; q < 16; ++q) { t.p[idx] = (unsigned char)p; t.q[idx] = (unsigned char)q; ++idx; }
  return t;
}
__constant__ TriLut LUT = make_lut();

__device__ __forceinline__ unsigned short f2bf(float f) {
  union { float f; unsigned u; } v; v.f = f;
  unsigned r = v.u + 0x7fffu + ((v.u >> 16) & 1u);   // RNE
  return (unsigned short)(r >> 16);
}
__device__ __forceinline__ unsigned pack2(float a, float b) {
  __hip_bfloat162 h = __float22bfloat162_rn(float2{a, b});   // low half = a
  union { __hip_bfloat162 h; unsigned u; } v; v.h = h;
  return v.u;
}
__device__ __forceinline__ float bf2f(unsigned short h) {
  union { unsigned u; float f; } v; v.u = ((unsigned)h) << 16;
  return v.f;
}

// ---- setup: pack symmetrized B' [n=384][k=160] bf16 into workspace ----
// cols 0..367: U3sym[(i,k3)]; 368..371: U2sym[k2]; 372: U1 in k-rows 136..151.
__global__ void build_bt(const float* __restrict__ U1, const float* __restrict__ U2,
                         const float* __restrict__ U3, unsigned short* __restrict__ bt) {
  int gid = blockIdx.x * 256 + threadIdx.x;
  if (gid >= NCOL * KPAD) return;
  int n  = gid / KPAD;
  int kk = gid - n * KPAD;
  float val = 0.f;
  if (kk < NTRI && n < 372) {
    int p = LUT.p[kk], q = LUT.q[kk];
    if (n < 368) {
      int i = n / NK3, k3 = n - i * NK3;
      val = U3[((p * 16 + q) * 16 + i) * NK3 + k3];
      if (p != q) val += U3[((q * 16 + p) * 16 + i) * NK3 + k3];
    } else {
      int k2 = n - 368;
      val = U2[(p * 16 + q) * NK2 + k2];
      if (p != q) val += U2[(q * 16 + p) * NK2 + k2];
    }
  } else if (n == 372 && kk >= 136 && kk < 152) {
    val = U1[kk - 136];   // pairs with XX k-slots 136..151 = x  ->  V[c,372] = sum_p U1_p x_p
  }
  bt[gid] = f2bf(val);
}

__device__ __forceinline__ void load_bfrag(short8 bf[3][5], const unsigned short* __restrict__ bt,
                                           int nbase, int l16, int quad) {
#pragma unroll
  for (int nt = 0; nt < 3; ++nt) {
    const unsigned short* src = bt + (size_t)(nbase + nt * 16 + l16) * KPAD + quad * 8;
#pragma unroll
    for (int ks = 0; ks < 5; ++ks)
      bf[nt][ks] = *(const short8*)(src + ks * 32);
  }
}

__device__ __forceinline__ void gemm_pass(f32x4 acc[8][3], const char* smem,
                                          const short8 bf[3][5], int l16, int quad) {
#pragma unroll
  for (int mt = 0; mt < 8; ++mt)
#pragma unroll
    for (int nt = 0; nt < 3; ++nt) acc[mt][nt] = (f32x4){0.f, 0.f, 0.f, 0.f};
#pragma unroll
  for (int ks = 0; ks < 5; ++ks) {
    short8 af[8];
#pragma unroll
    for (int mt = 0; mt < 8; ++mt)
      af[mt] = *(const short8*)(smem + XX_OFF + (mt * 16 + l16) * KSB + ks * 64 + quad * 16);
#pragma unroll
    for (int nt = 0; nt < 3; ++nt)
#pragma unroll
      for (int mt = 0; mt < 8; ++mt)
        acc[mt][nt] = __builtin_amdgcn_mfma_f32_16x16x32_bf16(af[mt], bf[nt][ks], acc[mt][nt], 0, 0, 0);
  }
}

__device__ __forceinline__ void epi_acc(float esum[8][4], const f32x4 acc[8][3], const char* smem,
                                        int nbase, int l16, int quad) {
  int ktab[3], irow[3];
  bool ux[3];
#pragma unroll
  for (int nt = 0; nt < 3; ++nt) {
    const int n = nbase + nt * 16 + l16;
    ux[nt] = (n < 368);
    const int i = n / NK3;
    irow[nt] = ux[nt] ? i : 0;
    ktab[nt] = ux[nt] ? (n - i * NK3) : (n - 345);  // 368..372 -> 23..27; 373..383 -> zero rows
  }
  const float* xt = (const float*)(smem + XT_OFF);
  const float* wt = (const float*)(smem + WT_OFF);
#pragma unroll
  for (int mt = 0; mt < 8; ++mt) {
    const int c4 = mt * 16 + quad * 4;
#pragma unroll
    for (int nt = 0; nt < 3; ++nt) {
      float4 wv = *(const float4*)(wt + ktab[nt] * WTS + c4);
      float4 xv = *(const float4*)(xt + irow[nt] * XTS + c4);
      const float f0 = ux[nt] ? xv.x : 1.f;
      const float f1 = ux[nt] ? xv.y : 1.f;
      const float f2 = ux[nt] ? xv.z : 1.f;
      const float f3 = ux[nt] ? xv.w : 1.f;
      esum[mt][0] += acc[mt][nt][0] * wv.x * f0;
      esum[mt][1] += acc[mt][nt][1] * wv.y * f1;
      esum[mt][2] += acc[mt][nt][2] * wv.z * f2;
      esum[mt][3] += acc[mt][nt][3] * wv.w * f3;
    }
  }
}

__global__ __launch_bounds__(256, 2) void mace_main(
    const float* __restrict__ x, const float* __restrict__ y,
    const float* __restrict__ W1, const float* __restrict__ W2,
    const float* __restrict__ W3,
    const unsigned short* __restrict__ bt, float* __restrict__ out) {
  __shared__ __align__(16) char smem[SMEM_BYTES];
  const int t  = threadIdx.x;
  const int b  = blockIdx.x;
  const int lane = t & 63, w = t >> 6;
  const int quad = lane >> 4, l16 = lane & 15;
  const int nbaseA = w * 96;        // pass A columns
  const int nbaseB = w * 96 + 48;   // pass B columns

  // ---- P0: pass-A B' fragments -> registers (L2-hot; consumed at P3a) ----
  short8 bfrag[3][5];
  load_bfrag(bfrag, bt, nbaseA, l16, quad);

  // ---- P1: stage x -> Xb (bf16 [c][i]) and XT (f32 [i][c]) ----
  {
    const float4* x4 = (const float4*)(x + (size_t)b * C_CH * L_DIM);
    float* xt = (float*)(smem + XT_OFF);
#pragma unroll
    for (int r = 0; r < 2; ++r) {
      const int o = t + r * 256;
      float4 f = x4[o];
      const int c = o >> 2, i0 = (o & 3) * 4;
      unsigned* xb = (unsigned*)((unsigned short*)(smem + XB_OFF) + c * 16 + i0);
      xb[0] = pack2(f.x, f.y);
      xb[1] = pack2(f.z, f.w);
      xt[(i0 + 0) * XTS + c] = f.x;
      xt[(i0 + 1) * XTS + c] = f.y;
      xt[(i0 + 2) * XTS + c] = f.z;
      xt[(i0 + 3) * XTS + c] = f.w;
    }
  }
  // ---- P1b: combined weights -> wtab[k][c] (k: 0..22 w3, 23..26 w2, 27 w1, 28..38 zero) ----
  {
    float yv[E_EL];
#pragma unroll
    for (int e = 0; e < E_EL; ++e) yv[e] = y[(size_t)b * E_EL + e];  // wave-uniform -> s_load
    float* wt = (float*)(smem + WT_OFF);
    for (int u = t; u < 39 * 32; u += 256) {
      const int k = u >> 5, cg = (u & 31) * 4;
      float4 a = {0.f, 0.f, 0.f, 0.f};
      if (k < 23) {
#pragma unroll
        for (int e = 0; e < E_EL; ++e) {
          float4 wv = *(const float4*)(W3 + (e * NK3 + k) * C_CH + cg);
          a.x += yv[e] * wv.x; a.y += yv[e] * wv.y; a.z += yv[e] * wv.z; a.w += yv[e] * wv.w;
        }
      } else if (k < 27) {
#pragma unroll
        for (int e = 0; e < E_EL; ++e) {
          float4 wv = *(const float4*)(W2 + (e * NK2 + (k - 23)) * C_CH + cg);
          a.x += yv[e] * wv.x; a.y += yv[e] * wv.y; a.z += yv[e] * wv.z; a.w += yv[e] * wv.w;
        }
      } else if (k == 27) {
#pragma unroll
        for (int e = 0; e < E_EL; ++e) {
          float4 wv = *(const float4*)(W1 + e * C_CH + cg);
          a.x += yv[e] * wv.x; a.y += yv[e] * wv.y; a.z += yv[e] * wv.z; a.w += yv[e] * wv.w;
        }
      }
      *(float4*)(wt + k * WTS + cg) = a;
    }
  }
  __syncthreads();
  // ---- P2: XX[c, 0..135] = x_p*x_q bf16; slots 136..151 = x (corr-1 rows); 152..159 = 0 ----
  {
    const int c = t >> 1, half = t & 1;
    const unsigned short* xr = (const unsigned short*)(smem + XB_OFF) + c * 16;
    short8 x0 = *(const short8*)(xr);
    short8 x1 = *(const short8*)(xr + 8);
    float xf[16];
#pragma unroll
    for (int i = 0; i < 8; ++i) {
      xf[i]     = bf2f((unsigned short)x0[i]);
      xf[i + 8] = bf2f((unsigned short)x1[i]);
    }
    unsigned* dst = (unsigned*)(smem + XX_OFF + c * KSB);
    float prev = 0.f;
    int idx = 0;
#pragma unroll
    for (int p = 0; p < 16; ++p) {
#pragma unroll
      for (int q = p; q < 16; ++q) {
        const bool mine = (idx < 68) == (half == 0);
        if (mine) {
          const float val = xf[p] * xf[q];
          if (idx & 1) dst[idx >> 1] = pack2(prev, val);
          else prev = val;
        }
        ++idx;
      }
    }
    if (half) {
      const unsigned* xp = (const unsigned*)xr;  // already-packed bf16 pairs
#pragma unroll
      for (int j = 0; j < 8; ++j) dst[68 + j] = xp[j];   // k 136..151 = x
#pragma unroll
      for (int j = 76; j < 80; ++j) dst[j] = 0u;         // k 152..159 = 0
    }
  }
  __syncthreads();
  // ---- P3a/P4a: pass A GEMM + epilogue-accumulate; pass-B frags load under epilogue ----
  float esum[8][4];
#pragma unroll
  for (int mt = 0; mt < 8; ++mt)
#pragma unroll
    for (int r = 0; r < 4; ++r) esum[mt][r] = 0.f;

  f32x4 acc[8][3];
  gemm_pass(acc, smem, bfrag, l16, quad);
  load_bfrag(bfrag, bt, nbaseB, l16, quad);  // reg reuse forces issue after last pass-A MFMA
  epi_acc(esum, acc, smem, nbaseA, l16, quad);

  // ---- P3b/P4b: pass B ----
  gemm_pass(acc, smem, bfrag, l16, quad);
  epi_acc(esum, acc, smem, nbaseB, l16, quad);

  // ---- P5: reduce over l16 (butterfly), stash wave partials, final plain store ----
#pragma unroll
  for (int mt = 0; mt < 8; ++mt)
#pragma unroll
    for (int m = 1; m <= 8; m <<= 1) {
      esum[mt][0] += __shfl_xor(esum[mt][0], m, 64);
      esum[mt][1] += __shfl_xor(esum[mt][1], m, 64);
      esum[mt][2] += __shfl_xor(esum[mt][2], m, 64);
      esum[mt][3] += __shfl_xor(esum[mt][3], m, 64);
    }
  float* ws = (float*)(smem + WS_OFF);
  if (l16 == 0) {
#pragma unroll
    for (int mt = 0; mt < 8; ++mt) {
      float4 v = {esum[mt][0], esum[mt][1], esum[mt][2], esum[mt][3]};
      *(float4*)(ws + w * C_CH + mt * 16 + quad * 4) = v;
    }
  }
  __syncthreads();
  if (t < C_CH) {
    float s = ws[t] + ws[C_CH + t] + ws[2 * C_CH + t] + ws[3 * C_CH + t];
    out[(size_t)b * C_CH + t] = s;
  }
}

extern "C" void kernel_launch(void* const* d_in, const int* in_sizes, int n_in,
                              void* d_out, int out_size, void* d_ws, size_t ws_size,
                              hipStream_t stream) {
  const float* x  = (const float*)d_in[0];
  const float* y  = (const float*)d_in[1];
  const float* U1 = (const float*)d_in[2];
  const float* U2 = (const float*)d_in[3];
  const float* U3 = (const float*)d_in[4];
  const float* W1 = (const float*)d_in[5];
  const float* W2 = (const float*)d_in[6];
  const float* W3 = (const float*)d_in[7];
  float* out = (float*)d_out;
  unsigned short* bt = (unsigned short*)d_ws;
  if (ws_size < (size_t)NCOL * KPAD * sizeof(unsigned short)) return;  // need 122,880 B scratch

  build_bt<<<dim3((NCOL * KPAD + 255) / 256), dim3(256), 0, stream>>>(U1, U2, U3, bt);
  mace_main<<<dim3(B_ATOMS), dim3(256), 0, stream>>>(x, y, W1, W2, W3, bt, out);
}

// Round 5
// 347.572 us; speedup vs baseline: 2.1554x; 2.1554x over previous
//
#include <hip/hip_runtime.h>
#include <hip/hip_bf16.h>
#include <stdint.h>

// ---- problem constants ----
#define B_ATOMS 8192
#define C_CH    128
#define L_DIM   16
#define E_EL    10
#define NK3     23
#define NK2     4
#define NTRI    136   // 16*17/2 upper-triangle pairs
#define KPAD    160   // K padded to 32-multiple for 16x16x32 MFMA
#define NCOL    384   // 368 (i*23+k3) + 4 (k2) + 1 (U1 col 372) + 11 pad
#define KSB     336   // XX LDS k-stride BYTES (168 bf16; 84 dwords = 20 mod 32 -> <=2-way b128)
#define XTS     132   // XT f32 row stride
#define WTS     132   // wtab f32 row stride

// ---- LDS layout (bytes) ----
#define XX_OFF  0          // 128*336               = 43008
#define XB_OFF  43008      // bf16 [c][16]          =  4096 -> 47104
#define XT_OFF  47104      // f32 [16][132]         =  8448 -> 55552
#define WT_OFF  55552      // f32 [39][132]         = 20592 -> 76144
#define WS_OFF  76144      // f32 [4][128]          =  2048 -> 78192
#define SMEM_BYTES 78192   // x2 = 156384 <= 163840 -> 2 blocks/CU

typedef __attribute__((ext_vector_type(8))) short short8;
typedef __attribute__((ext_vector_type(4))) float f32x4;

struct TriLut { unsigned char p[NTRI]; unsigned char q[NTRI]; };
static constexpr TriLut make_lut() {
  TriLut t{};
  int idx = 0;
  for (int p = 0; p < 16; ++p)
    for (int q = p; q < 16; ++q) { t.p[idx] = (unsigned char)p; t.q[idx] = (unsigned char)q; ++idx; }
  return t;
}
__constant__ TriLut LUT = make_lut();

__device__ __forceinline__ unsigned short f2bf(float f) {
  union { float f; unsigned u; } v; v.f = f;
  unsigned r = v.u + 0x7fffu + ((v.u >> 16) & 1u);   // RNE
  return (unsigned short)(r >> 16);
}
__device__ __forceinline__ unsigned pack2(float a, float b) {
  __hip_bfloat162 h = __float22bfloat162_rn(float2{a, b});   // low half = a
  union { __hip_bfloat162 h; unsigned u; } v; v.h = h;
  return v.u;
}
__device__ __forceinline__ float bf2f(unsigned short h) {
  union { unsigned u; float f; } v; v.u = ((unsigned)h) << 16;
  return v.f;
}

// ---- setup: pack symmetrized B' [n=384][k=160] bf16 into workspace ----
// cols 0..367: U3sym[(i,k3)]; 368..371: U2sym[k2]; 372: U1 in k-rows 136..151.
__global__ void build_bt(const float* __restrict__ U1, const float* __restrict__ U2,
                         const float* __restrict__ U3, unsigned short* __restrict__ bt) {
  int gid = blockIdx.x * 256 + threadIdx.x;
  if (gid >= NCOL * KPAD) return;
  int n  = gid / KPAD;
  int kk = gid - n * KPAD;
  float val = 0.f;
  if (kk < NTRI && n < 372) {
    int p = LUT.p[kk], q = LUT.q[kk];
    if (n < 368) {
      int i = n / NK3, k3 = n - i * NK3;
      val = U3[((p * 16 + q) * 16 + i) * NK3 + k3];
      if (p != q) val += U3[((q * 16 + p) * 16 + i) * NK3 + k3];
    } else {
      int k2 = n - 368;
      val = U2[(p * 16 + q) * NK2 + k2];
      if (p != q) val += U2[(q * 16 + p) * NK2 + k2];
    }
  } else if (n == 372 && kk >= 136 && kk < 152) {
    val = U1[kk - 136];   // pairs with XX k-slots 136..151 = x  ->  V[c,372] = sum_p U1_p x_p
  }
  bt[gid] = f2bf(val);
}

// One 48-column pass: load B' frags, GEMM, weighted epilogue, butterfly-reduce,
// accumulate wave partials into ws (LDS). No persistent registers across passes.
template <bool FIRST>
__device__ __forceinline__ void do_pass(const char* __restrict__ smem, float* __restrict__ ws,
                                        const unsigned short* __restrict__ bt,
                                        int nbase, int w, int l16, int quad) {
  // B' fragments -> registers (L2-hot)
  short8 bfrag[3][5];
#pragma unroll
  for (int nt = 0; nt < 3; ++nt) {
    const unsigned short* src = bt + (size_t)(nbase + nt * 16 + l16) * KPAD + quad * 8;
#pragma unroll
    for (int ks = 0; ks < 5; ++ks)
      bfrag[nt][ks] = *(const short8*)(src + ks * 32);
  }
  // GEMM: V[128 x 48] = XX[128 x 160] * B'[160 x 48]
  f32x4 acc[8][3];
#pragma unroll
  for (int mt = 0; mt < 8; ++mt)
#pragma unroll
    for (int nt = 0; nt < 3; ++nt) acc[mt][nt] = (f32x4){0.f, 0.f, 0.f, 0.f};
#pragma unroll
  for (int ks = 0; ks < 5; ++ks) {
    short8 af[8];
#pragma unroll
    for (int mt = 0; mt < 8; ++mt)
      af[mt] = *(const short8*)(smem + XX_OFF + (mt * 16 + l16) * KSB + ks * 64 + quad * 16);
#pragma unroll
    for (int nt = 0; nt < 3; ++nt)
#pragma unroll
      for (int mt = 0; mt < 8; ++mt)
        acc[mt][nt] = __builtin_amdgcn_mfma_f32_16x16x32_bf16(af[mt], bfrag[nt][ks], acc[mt][nt], 0, 0, 0);
  }
  // epilogue decode (per-lane n -> (i, k))
  int ktab[3], irow[3];
  bool ux[3];
#pragma unroll
  for (int nt = 0; nt < 3; ++nt) {
    const int n = nbase + nt * 16 + l16;
    ux[nt] = (n < 368);
    const int i = n / NK3;
    irow[nt] = ux[nt] ? i : 0;
    ktab[nt] = ux[nt] ? (n - i * NK3) : (n - 345);  // 368..372 -> 23..27; 373..383 -> zero rows
  }
  const float* xt = (const float*)(smem + XT_OFF);
  const float* wt = (const float*)(smem + WT_OFF);
#pragma unroll
  for (int mt = 0; mt < 8; ++mt) {
    const int c4 = mt * 16 + quad * 4;
    float s0 = 0.f, s1 = 0.f, s2 = 0.f, s3 = 0.f;
#pragma unroll
    for (int nt = 0; nt < 3; ++nt) {
      float4 wv = *(const float4*)(wt + ktab[nt] * WTS + c4);
      float4 xv = *(const float4*)(xt + irow[nt] * XTS + c4);
      const float f0 = ux[nt] ? xv.x : 1.f;
      const float f1 = ux[nt] ? xv.y : 1.f;
      const float f2 = ux[nt] ? xv.z : 1.f;
      const float f3 = ux[nt] ? xv.w : 1.f;
      s0 += acc[mt][nt][0] * wv.x * f0;
      s1 += acc[mt][nt][1] * wv.y * f1;
      s2 += acc[mt][nt][2] * wv.z * f2;
      s3 += acc[mt][nt][3] * wv.w * f3;
    }
#pragma unroll
    for (int m = 1; m <= 8; m <<= 1) {
      s0 += __shfl_xor(s0, m, 64);
      s1 += __shfl_xor(s1, m, 64);
      s2 += __shfl_xor(s2, m, 64);
      s3 += __shfl_xor(s3, m, 64);
    }
    if (l16 == 0) {
      float* dst = ws + w * C_CH + c4;
      if (FIRST) {
        *(float4*)dst = (float4){s0, s1, s2, s3};
      } else {
        float4 old = *(const float4*)dst;
        *(float4*)dst = (float4){old.x + s0, old.y + s1, old.z + s2, old.w + s3};
      }
    }
  }
}

__global__ __launch_bounds__(256, 2) void mace_main(
    const float* __restrict__ x, const float* __restrict__ y,
    const float* __restrict__ W1, const float* __restrict__ W2,
    const float* __restrict__ W3,
    const unsigned short* __restrict__ bt, float* __restrict__ out) {
  __shared__ __align__(16) char smem[SMEM_BYTES];
  const int t  = threadIdx.x;
  const int b  = blockIdx.x;
  const int lane = t & 63, w = t >> 6;
  const int quad = lane >> 4, l16 = lane & 15;

  // ---- P1: stage x -> Xb (bf16 [c][i]) and XT (f32 [i][c]) ----
  {
    const float4* x4 = (const float4*)(x + (size_t)b * C_CH * L_DIM);
    float* xt = (float*)(smem + XT_OFF);
#pragma unroll
    for (int r = 0; r < 2; ++r) {
      const int o = t + r * 256;
      float4 f = x4[o];
      const int c = o >> 2, i0 = (o & 3) * 4;
      unsigned* xb = (unsigned*)((unsigned short*)(smem + XB_OFF) + c * 16 + i0);
      xb[0] = pack2(f.x, f.y);
      xb[1] = pack2(f.z, f.w);
      xt[(i0 + 0) * XTS + c] = f.x;
      xt[(i0 + 1) * XTS + c] = f.y;
      xt[(i0 + 2) * XTS + c] = f.z;
      xt[(i0 + 3) * XTS + c] = f.w;
    }
  }
  // ---- P1b: combined weights -> wtab[k][c] (k: 0..22 w3, 23..26 w2, 27 w1, 28..38 zero) ----
  {
    float yv[E_EL];
#pragma unroll
    for (int e = 0; e < E_EL; ++e) yv[e] = y[(size_t)b * E_EL + e];  // wave-uniform -> s_load
    float* wt = (float*)(smem + WT_OFF);
    for (int u = t; u < 39 * 32; u += 256) {
      const int k = u >> 5, cg = (u & 31) * 4;
      float4 a = {0.f, 0.f, 0.f, 0.f};
      if (k < 23) {
#pragma unroll
        for (int e = 0; e < E_EL; ++e) {
          float4 wv = *(const float4*)(W3 + (e * NK3 + k) * C_CH + cg);
          a.x += yv[e] * wv.x; a.y += yv[e] * wv.y; a.z += yv[e] * wv.z; a.w += yv[e] * wv.w;
        }
      } else if (k < 27) {
#pragma unroll
        for (int e = 0; e < E_EL; ++e) {
          float4 wv = *(const float4*)(W2 + (e * NK2 + (k - 23)) * C_CH + cg);
          a.x += yv[e] * wv.x; a.y += yv[e] * wv.y; a.z += yv[e] * wv.z; a.w += yv[e] * wv.w;
        }
      } else if (k == 27) {
#pragma unroll
        for (int e = 0; e < E_EL; ++e) {
          float4 wv = *(const float4*)(W1 + e * C_CH + cg);
          a.x += yv[e] * wv.x; a.y += yv[e] * wv.y; a.z += yv[e] * wv.z; a.w += yv[e] * wv.w;
        }
      }
      *(float4*)(wt + k * WTS + cg) = a;
    }
  }
  __syncthreads();
  // ---- P2: XX[c, 0..135] = x_p*x_q bf16; slots 136..151 = x (corr-1 rows); 152..159 = 0 ----
  {
    const int c = t >> 1, half = t & 1;
    const unsigned short* xr = (const unsigned short*)(smem + XB_OFF) + c * 16;
    short8 x0 = *(const short8*)(xr);
    short8 x1 = *(const short8*)(xr + 8);
    float xf[16];
#pragma unroll
    for (int i = 0; i < 8; ++i) {
      xf[i]     = bf2f((unsigned short)x0[i]);
      xf[i + 8] = bf2f((unsigned short)x1[i]);
    }
    unsigned* dst = (unsigned*)(smem + XX_OFF + c * KSB);
    float prev = 0.f;
    int idx = 0;
#pragma unroll
    for (int p = 0; p < 16; ++p) {
#pragma unroll
      for (int q = p; q < 16; ++q) {
        const bool mine = (idx < 68) == (half == 0);
        if (mine) {
          const float val = xf[p] * xf[q];
          if (idx & 1) dst[idx >> 1] = pack2(prev, val);
          else prev = val;
        }
        ++idx;
      }
    }
    if (half) {
      const unsigned* xp = (const unsigned*)xr;  // already-packed bf16 pairs
#pragma unroll
      for (int j = 0; j < 8; ++j) dst[68 + j] = xp[j];   // k 136..151 = x
#pragma unroll
      for (int j = 76; j < 80; ++j) dst[j] = 0u;         // k 152..159 = 0
    }
  }
  __syncthreads();
  // ---- two 48-column passes; wave partials accumulate in LDS ws ----
  float* ws = (float*)(smem + WS_OFF);
  do_pass<true >(smem, ws, bt, w * 96,      w, l16, quad);
  do_pass<false>(smem, ws, bt, w * 96 + 48, w, l16, quad);
  __syncthreads();
  // ---- final: sum 4 wave partials, plain coalesced store ----
  if (t < C_CH) {
    float s = ws[t] + ws[C_CH + t] + ws[2 * C_CH + t] + ws[3 * C_CH + t];
    out[(size_t)b * C_CH + t] = s;
  }
}

extern "C" void kernel_launch(void* const* d_in, const int* in_sizes, int n_in,
                              void* d_out, int out_size, void* d_ws, size_t ws_size,
                              hipStream_t stream) {
  const float* x  = (const float*)d_in[0];
  const float* y  = (const float*)d_in[1];
  const float* U1 = (const float*)d_in[2];
  const float* U2 = (const float*)d_in[3];
  const float* U3 = (const float*)d_in[4];
  const float* W1 = (const float*)d_in[5];
  const float* W2 = (const float*)d_in[6];
  const float* W3 = (const float*)d_in[7];
  float* out = (float*)d_out;
  unsigned short* bt = (unsigned short*)d_ws;
  if (ws_size < (size_t)NCOL * KPAD * sizeof(unsigned short)) return;  // need 122,880 B scratch

  build_bt<<<dim3((NCOL * KPAD + 255) / 256), dim3(256), 0, stream>>>(U1, U2, U3, bt);
  mace_main<<<dim3(B_ATOMS), dim3(256), 0, stream>>>(x, y, W1, W2, W3, bt, out);
}

// Round 6
// 304.357 us; speedup vs baseline: 2.4614x; 1.1420x over previous
//
#include <hip/hip_runtime.h>
#include <hip/hip_bf16.h>
#include <stdint.h>

// ---- problem constants ----
#define B_ATOMS 8192
#define C_CH    128
#define L_DIM   16
#define E_EL    10
#define NK3     23
#define NK2     4
#define NTRI    136   // 16*17/2 upper-triangle pairs
#define KPAD    160   // K padded to 32-multiple for 16x16x32 MFMA
#define NCOL    384   // 368 (i*23+k3) + 4 (k2) + 1 (U1 col 372) + 11 pad
#define KSB     336   // XX LDS k-stride BYTES (168 bf16; 84 dwords = 20 mod 32 -> <=2-way b128)
#define TSE     136   // bf16 table row stride, elems (272 B; b64-aligned, <=4-way on wv)

// ---- LDS layout (bytes) ----
#define XX_OFF  0          // 128*336            = 43008
#define XB_OFF  43008      // bf16 [c][16]       =  4096 -> 47104
#define XT_OFF  47104      // bf16 [17][136]     =  4624 -> 51728  (row 16 = ones)
#define WT_OFF  51728      // bf16 [39][136]     = 10608 -> 62336  (rows 28..38 zero)
#define WS_OFF  62336      // f32 [4][128]       =  2048 -> 64384
#define SMEM_BYTES 64384   // x2 = 128768 <= 163840 -> 2 blocks/CU

typedef __attribute__((ext_vector_type(8))) short short8;
typedef __attribute__((ext_vector_type(4))) float f32x4;

struct TriLut { unsigned char p[NTRI]; unsigned char q[NTRI]; };
static constexpr TriLut make_lut() {
  TriLut t{};
  int idx = 0;
  for (int p = 0; p < 16; ++p)
    for (int q = p; q < 16; ++q) { t.p[idx] = (unsigned char)p; t.q[idx] = (unsigned char)q; ++idx; }
  return t;
}
__constant__ TriLut LUT = make_lut();

__device__ __forceinline__ unsigned short f2bf(float f) {
  union { float f; unsigned u; } v; v.f = f;
  unsigned r = v.u + 0x7fffu + ((v.u >> 16) & 1u);   // RNE
  return (unsigned short)(r >> 16);
}
__device__ __forceinline__ unsigned pack2(float a, float b) {
  __hip_bfloat162 h = __float22bfloat162_rn(float2{a, b});   // low half = a
  union { __hip_bfloat162 h; unsigned u; } v; v.h = h;
  return v.u;
}
__device__ __forceinline__ float bf2f(unsigned short h) {
  union { unsigned u; float f; } v; v.u = ((unsigned)h) << 16;
  return v.f;
}
__device__ __forceinline__ float2 bfup(unsigned u) {   // unpack bf16 pair -> 2 floats
  float2 r;
  r.x = __uint_as_float(u << 16);
  r.y = __uint_as_float(u & 0xffff0000u);
  return r;
}
// 16-lane (DPP row) inclusive-sum step; after 1,2,4,8 lane15 holds the row sum.
template <int CTRL>
__device__ __forceinline__ float dpp_add(float s) {
  int v = __builtin_amdgcn_update_dpp(0, __float_as_int(s), CTRL, 0xf, 0xf, true);
  return s + __int_as_float(v);
}
__device__ __forceinline__ float row16_sum(float s) {
  s = dpp_add<0x111>(s);  // row_shr:1
  s = dpp_add<0x112>(s);  // row_shr:2
  s = dpp_add<0x114>(s);  // row_shr:4
  s = dpp_add<0x118>(s);  // row_shr:8
  return s;
}

// ---- setup: pack symmetrized B' [n=384][k=160] bf16 into workspace ----
// cols 0..367: U3sym[(i,k3)]; 368..371: U2sym[k2]; 372: U1 in k-rows 136..151.
__global__ void build_bt(const float* __restrict__ U1, const float* __restrict__ U2,
                         const float* __restrict__ U3, unsigned short* __restrict__ bt) {
  int gid = blockIdx.x * 256 + threadIdx.x;
  if (gid >= NCOL * KPAD) return;
  int n  = gid / KPAD;
  int kk = gid - n * KPAD;
  float val = 0.f;
  if (kk < NTRI && n < 372) {
    int p = LUT.p[kk], q = LUT.q[kk];
    if (n < 368) {
      int i = n / NK3, k3 = n - i * NK3;
      val = U3[((p * 16 + q) * 16 + i) * NK3 + k3];
      if (p != q) val += U3[((q * 16 + p) * 16 + i) * NK3 + k3];
    } else {
      int k2 = n - 368;
      val = U2[(p * 16 + q) * NK2 + k2];
      if (p != q) val += U2[(q * 16 + p) * NK2 + k2];
    }
  } else if (n == 372 && kk >= 136 && kk < 152) {
    val = U1[kk - 136];   // pairs with XX k-slots 136..151 = x  ->  V[c,372] = sum_p U1_p x_p
  }
  bt[gid] = f2bf(val);
}

// One 48-column pass: B' frags from global, GEMM, weighted epilogue (bf16 tables),
// DPP row-reduce, accumulate wave partials in ws (LDS). No cross-pass registers.
template <bool FIRST>
__device__ __forceinline__ void do_pass(const char* __restrict__ smem, float* __restrict__ ws,
                                        const unsigned short* __restrict__ bt,
                                        int nbase, int w, int l16, int quad) {
  // B' fragments -> registers (L2-hot)
  short8 bfrag[3][5];
#pragma unroll
  for (int nt = 0; nt < 3; ++nt) {
    const unsigned short* src = bt + (size_t)(nbase + nt * 16 + l16) * KPAD + quad * 8;
#pragma unroll
    for (int ks = 0; ks < 5; ++ks)
      bfrag[nt][ks] = *(const short8*)(src + ks * 32);
  }
  // GEMM: V[128 x 48] = XX[128 x 160] * B'[160 x 48]
  f32x4 acc[8][3];
#pragma unroll
  for (int mt = 0; mt < 8; ++mt)
#pragma unroll
    for (int nt = 0; nt < 3; ++nt) acc[mt][nt] = (f32x4){0.f, 0.f, 0.f, 0.f};
#pragma unroll
  for (int ks = 0; ks < 5; ++ks) {
    short8 af[8];
#pragma unroll
    for (int mt = 0; mt < 8; ++mt)
      af[mt] = *(const short8*)(smem + XX_OFF + (mt * 16 + l16) * KSB + ks * 64 + quad * 16);
#pragma unroll
    for (int nt = 0; nt < 3; ++nt)
#pragma unroll
      for (int mt = 0; mt < 8; ++mt)
        acc[mt][nt] = __builtin_amdgcn_mfma_f32_16x16x32_bf16(af[mt], bfrag[nt][ks], acc[mt][nt], 0, 0, 0);
  }
  // epilogue decode: irow = n/23 (naturally 16 = ones-row for n>=368)
  int ktab[3], irow[3];
#pragma unroll
  for (int nt = 0; nt < 3; ++nt) {
    const int n = nbase + nt * 16 + l16;
    const int i = n / NK3;
    irow[nt] = i;                                      // 16 for n>=368 -> XT ones row
    ktab[nt] = (n < 368) ? (n - i * NK3) : (n - 345);  // 368..372 -> 23..27; 373.. -> zero rows
  }
  const unsigned short* xt = (const unsigned short*)(smem + XT_OFF);
  const unsigned short* wt = (const unsigned short*)(smem + WT_OFF);
#pragma unroll
  for (int mt = 0; mt < 8; ++mt) {
    const int c4 = mt * 16 + quad * 4;
    float s0 = 0.f, s1 = 0.f, s2 = 0.f, s3 = 0.f;
#pragma unroll
    for (int nt = 0; nt < 3; ++nt) {
      uint2 wv = *(const uint2*)(wt + ktab[nt] * TSE + c4);
      uint2 xv = *(const uint2*)(xt + irow[nt] * TSE + c4);
      float2 w01 = bfup(wv.x), w23 = bfup(wv.y);
      float2 x01 = bfup(xv.x), x23 = bfup(xv.y);
      s0 += acc[mt][nt][0] * (w01.x * x01.x);
      s1 += acc[mt][nt][1] * (w01.y * x01.y);
      s2 += acc[mt][nt][2] * (w23.x * x23.x);
      s3 += acc[mt][nt][3] * (w23.y * x23.y);
    }
    s0 = row16_sum(s0);
    s1 = row16_sum(s1);
    s2 = row16_sum(s2);
    s3 = row16_sum(s3);
    if (l16 == 15) {
      float* dst = ws + w * C_CH + c4;
      if (FIRST) {
        *(float4*)dst = (float4){s0, s1, s2, s3};
      } else {
        float4 old = *(const float4*)dst;
        *(float4*)dst = (float4){old.x + s0, old.y + s1, old.z + s2, old.w + s3};
      }
    }
  }
}

__global__ __launch_bounds__(256, 2) void mace_main(
    const float* __restrict__ x, const float* __restrict__ y,
    const float* __restrict__ W1, const float* __restrict__ W2,
    const float* __restrict__ W3,
    const unsigned short* __restrict__ bt, float* __restrict__ out) {
  __shared__ __align__(16) char smem[SMEM_BYTES];
  const int t  = threadIdx.x;
  const int b  = blockIdx.x;
  const int lane = t & 63, w = t >> 6;
  const int quad = lane >> 4, l16 = lane & 15;

  // ---- P1: stage x -> XB (bf16 [c][i], MFMA A-side) and XT (bf16 [i][c] + ones row) ----
  {
    const float4* x4 = (const float4*)(x + (size_t)b * C_CH * L_DIM);
    unsigned short* xtb = (unsigned short*)(smem + XT_OFF);
#pragma unroll
    for (int r = 0; r < 2; ++r) {
      const int o = t + r * 256;
      float4 f = x4[o];
      const int c = o >> 2, i0 = (o & 3) * 4;
      unsigned* xb = (unsigned*)((unsigned short*)(smem + XB_OFF) + c * 16 + i0);
      xb[0] = pack2(f.x, f.y);
      xb[1] = pack2(f.z, f.w);
      xtb[(i0 + 0) * TSE + c] = f2bf(f.x);
      xtb[(i0 + 1) * TSE + c] = f2bf(f.y);
      xtb[(i0 + 2) * TSE + c] = f2bf(f.z);
      xtb[(i0 + 3) * TSE + c] = f2bf(f.w);
    }
    if (t < C_CH) xtb[16 * TSE + t] = 0x3f80;   // ones row (bf16 1.0)
  }
  // ---- P1b: combined weights -> wt bf16 [k][c] (k: 0..22 w3, 23..26 w2, 27 w1, 28..38 zero) ----
  {
    float yv[E_EL];
#pragma unroll
    for (int e = 0; e < E_EL; ++e) yv[e] = y[(size_t)b * E_EL + e];  // wave-uniform -> s_load
    unsigned short* wtb = (unsigned short*)(smem + WT_OFF);
    for (int u = t; u < 39 * 32; u += 256) {
      const int k = u >> 5, cg = (u & 31) * 4;
      float4 a = {0.f, 0.f, 0.f, 0.f};
      if (k < 23) {
#pragma unroll
        for (int e = 0; e < E_EL; ++e) {
          float4 wv = *(const float4*)(W3 + (e * NK3 + k) * C_CH + cg);
          a.x += yv[e] * wv.x; a.y += yv[e] * wv.y; a.z += yv[e] * wv.z; a.w += yv[e] * wv.w;
        }
      } else if (k < 27) {
#pragma unroll
        for (int e = 0; e < E_EL; ++e) {
          float4 wv = *(const float4*)(W2 + (e * NK2 + (k - 23)) * C_CH + cg);
          a.x += yv[e] * wv.x; a.y += yv[e] * wv.y; a.z += yv[e] * wv.z; a.w += yv[e] * wv.w;
        }
      } else if (k == 27) {
#pragma unroll
        for (int e = 0; e < E_EL; ++e) {
          float4 wv = *(const float4*)(W1 + e * C_CH + cg);
          a.x += yv[e] * wv.x; a.y += yv[e] * wv.y; a.z += yv[e] * wv.z; a.w += yv[e] * wv.w;
        }
      }
      uint2 pw;
      pw.x = pack2(a.x, a.y);
      pw.y = pack2(a.z, a.w);
      *(uint2*)(wtb + k * TSE + cg) = pw;
    }
  }
  __syncthreads();
  // ---- P2: XX[c, 0..135] = x_p*x_q bf16; slots 136..151 = x (corr-1 rows); 152..159 = 0 ----
  {
    const int c = t >> 1, half = t & 1;
    const unsigned short* xr = (const unsigned short*)(smem + XB_OFF) + c * 16;
    short8 x0 = *(const short8*)(xr);
    short8 x1 = *(const short8*)(xr + 8);
    float xf[16];
#pragma unroll
    for (int i = 0; i < 8; ++i) {
      xf[i]     = bf2f((unsigned short)x0[i]);
      xf[i + 8] = bf2f((unsigned short)x1[i]);
    }
    unsigned* dst = (unsigned*)(smem + XX_OFF + c * KSB);
    float prev = 0.f;
    int idx = 0;
#pragma unroll
    for (int p = 0; p < 16; ++p) {
#pragma unroll
      for (int q = p; q < 16; ++q) {
        const bool mine = (idx < 68) == (half == 0);
        if (mine) {
          const float val = xf[p] * xf[q];
          if (idx & 1) dst[idx >> 1] = pack2(prev, val);
          else prev = val;
        }
        ++idx;
      }
    }
    if (half) {
      const unsigned* xp = (const unsigned*)xr;  // already-packed bf16 pairs
#pragma unroll
      for (int j = 0; j < 8; ++j) dst[68 + j] = xp[j];   // k 136..151 = x
#pragma unroll
      for (int j = 76; j < 80; ++j) dst[j] = 0u;         // k 152..159 = 0
    }
  }
  __syncthreads();
  // ---- two 48-column passes; wave partials accumulate in LDS ws ----
  float* ws = (float*)(smem + WS_OFF);
  do_pass<true >(smem, ws, bt, w * 96,      w, l16, quad);
  do_pass<false>(smem, ws, bt, w * 96 + 48, w, l16, quad);
  __syncthreads();
  // ---- final: sum 4 wave partials, plain coalesced store ----
  if (t < C_CH) {
    float s = ws[t] + ws[C_CH + t] + ws[2 * C_CH + t] + ws[3 * C_CH + t];
    out[(size_t)b * C_CH + t] = s;
  }
}

extern "C" void kernel_launch(void* const* d_in, const int* in_sizes, int n_in,
                              void* d_out, int out_size, void* d_ws, size_t ws_size,
                              hipStream_t stream) {
  const float* x  = (const float*)d_in[0];
  const float* y  = (const float*)d_in[1];
  const float* U1 = (const float*)d_in[2];
  const float* U2 = (const float*)d_in[3];
  const float* U3 = (const float*)d_in[4];
  const float* W1 = (const float*)d_in[5];
  const float* W2 = (const float*)d_in[6];
  const float* W3 = (const float*)d_in[7];
  float* out = (float*)d_out;
  unsigned short* bt = (unsigned short*)d_ws;
  if (ws_size < (size_t)NCOL * KPAD * sizeof(unsigned short)) return;  // need 122,880 B scratch

  build_bt<<<dim3((NCOL * KPAD + 255) / 256), dim3(256), 0, stream>>>(U1, U2, U3, bt);
  mace_main<<<dim3(B_ATOMS), dim3(256), 0, stream>>>(x, y, W1, W2, W3, bt, out);
}

// Round 7
// 296.554 us; speedup vs baseline: 2.5262x; 1.0263x over previous
//
#include <hip/hip_runtime.h>
#include <hip/hip_bf16.h>
#include <stdint.h>

// ---- problem constants ----
#define B_ATOMS 8192
#define C_CH    128
#define CHB     64    // channels per block (c-half)
#define L_DIM   16
#define E_EL    10
#define NK3     23
#define NK2     4
#define NTRI    136   // 16*17/2 upper-triangle pairs
#define KPAD    160   // K padded to 32-multiple for 16x16x32 MFMA
#define NCOL    384   // 368 (i*23+k3) + 4 (k2) + 1 (U1 col 372) + 11 pad
#define KSB     336   // XX LDS k-stride BYTES (168 bf16; 84 dw = 20 mod 32 -> <=2-way b128)
#define TSE     72    // bf16 table row stride, elems (144 B = 36 dw = 4 mod 32; 8B-aligned)

// ---- LDS layout (bytes) ----
#define XX_OFF  0          // 64*336          = 21504
#define XT_OFF  21504      // bf16 [17][72]   =  2448 -> 23952  (row 16 = ones)
#define WT_OFF  23952      // bf16 [29][72]   =  4176 -> 28128  (row 28 = zero)
#define WS_OFF  28128      // f32 [4][64]     =  1024 -> 29152
#define SMEM_BYTES 29152   // 29.1 KB -> LDS allows 5 blocks/CU; VGPR (<=128) gives 4

typedef __attribute__((ext_vector_type(8))) short short8;
typedef __attribute__((ext_vector_type(4))) float f32x4;

struct TriLut { unsigned char p[NTRI]; unsigned char q[NTRI]; };
static constexpr TriLut make_lut() {
  TriLut t{};
  int idx = 0;
  for (int p = 0; p < 16; ++p)
    for (int q = p; q < 16; ++q) { t.p[idx] = (unsigned char)p; t.q[idx] = (unsigned char)q; ++idx; }
  return t;
}
__constant__ TriLut LUT = make_lut();

__device__ __forceinline__ unsigned short f2bf(float f) {
  union { float f; unsigned u; } v; v.f = f;
  unsigned r = v.u + 0x7fffu + ((v.u >> 16) & 1u);   // RNE
  return (unsigned short)(r >> 16);
}
__device__ __forceinline__ unsigned pack2(float a, float b) {
  __hip_bfloat162 h = __float22bfloat162_rn(float2{a, b});   // low half = a
  union { __hip_bfloat162 h; unsigned u; } v; v.h = h;
  return v.u;
}
__device__ __forceinline__ float2 bfup(unsigned u) {   // unpack bf16 pair -> 2 floats
  float2 r;
  r.x = __uint_as_float(u << 16);
  r.y = __uint_as_float(u & 0xffff0000u);
  return r;
}
// 16-lane (DPP row) reduce; after shr 1,2,4,8 lane15 holds the row sum.
template <int CTRL>
__device__ __forceinline__ float dpp_add(float s) {
  int v = __builtin_amdgcn_update_dpp(0, __float_as_int(s), CTRL, 0xf, 0xf, true);
  return s + __int_as_float(v);
}
__device__ __forceinline__ float row16_sum(float s) {
  s = dpp_add<0x111>(s);  // row_shr:1
  s = dpp_add<0x112>(s);  // row_shr:2
  s = dpp_add<0x114>(s);  // row_shr:4
  s = dpp_add<0x118>(s);  // row_shr:8
  return s;
}

// ---- setup: pack symmetrized B' [n=384][k=160] bf16 into workspace ----
// cols 0..367: U3sym[(i,k3)]; 368..371: U2sym[k2]; 372: U1 in k-rows 136..151.
__global__ void build_bt(const float* __restrict__ U1, const float* __restrict__ U2,
                         const float* __restrict__ U3, unsigned short* __restrict__ bt) {
  int gid = blockIdx.x * 256 + threadIdx.x;
  if (gid >= NCOL * KPAD) return;
  int n  = gid / KPAD;
  int kk = gid - n * KPAD;
  float val = 0.f;
  if (kk < NTRI && n < 372) {
    int p = LUT.p[kk], q = LUT.q[kk];
    if (n < 368) {
      int i = n / NK3, k3 = n - i * NK3;
      val = U3[((p * 16 + q) * 16 + i) * NK3 + k3];
      if (p != q) val += U3[((q * 16 + p) * 16 + i) * NK3 + k3];
    } else {
      int k2 = n - 368;
      val = U2[(p * 16 + q) * NK2 + k2];
      if (p != q) val += U2[(q * 16 + p) * NK2 + k2];
    }
  } else if (n == 372 && kk >= 136 && kk < 152) {
    val = U1[kk - 136];   // pairs with XX k-slots 136..151 = x  ->  V[c,372] = sum_p U1_p x_p
  }
  bt[gid] = f2bf(val);
}

// One 48-column pass: B' frags streamed from global per ks (1-deep prefetch),
// GEMM (64 rows x 48 cols), weighted epilogue, DPP reduce, wave partials in ws.
template <bool FIRST>
__device__ __forceinline__ void do_pass(const char* __restrict__ smem, float* __restrict__ ws,
                                        const unsigned short* __restrict__ bt,
                                        int nbase, int w, int l16, int quad) {
  const unsigned short* bp[3];
#pragma unroll
  for (int nt = 0; nt < 3; ++nt)
    bp[nt] = bt + (size_t)(nbase + nt * 16 + l16) * KPAD + quad * 8;

  short8 bcur[3], bnxt[3];
#pragma unroll
  for (int nt = 0; nt < 3; ++nt) bcur[nt] = *(const short8*)(bp[nt]);

  f32x4 acc[4][3];
#pragma unroll
  for (int mt = 0; mt < 4; ++mt)
#pragma unroll
    for (int nt = 0; nt < 3; ++nt) acc[mt][nt] = (f32x4){0.f, 0.f, 0.f, 0.f};

#pragma unroll
  for (int ks = 0; ks < 5; ++ks) {
    if (ks < 4) {
#pragma unroll
      for (int nt = 0; nt < 3; ++nt) bnxt[nt] = *(const short8*)(bp[nt] + (ks + 1) * 32);
    }
    short8 af[4];
#pragma unroll
    for (int mt = 0; mt < 4; ++mt)
      af[mt] = *(const short8*)(smem + XX_OFF + (mt * 16 + l16) * KSB + ks * 64 + quad * 16);
#pragma unroll
    for (int nt = 0; nt < 3; ++nt)
#pragma unroll
      for (int mt = 0; mt < 4; ++mt)
        acc[mt][nt] = __builtin_amdgcn_mfma_f32_16x16x32_bf16(af[mt], bcur[nt], acc[mt][nt], 0, 0, 0);
#pragma unroll
    for (int nt = 0; nt < 3; ++nt) bcur[nt] = bnxt[nt];
  }

  // epilogue decode: irow = n/23 (16 = ones row for n>=368); ktab clamped to zero-row 28
  int ktab[3], irow[3];
#pragma unroll
  for (int nt = 0; nt < 3; ++nt) {
    const int n = nbase + nt * 16 + l16;
    const int i = n / NK3;
    irow[nt] = i;
    ktab[nt] = (n < 368) ? (n - i * NK3) : min(n - 345, 28);
  }
  const unsigned short* xt = (const unsigned short*)(smem + XT_OFF);
  const unsigned short* wt = (const unsigned short*)(smem + WT_OFF);
#pragma unroll
  for (int mt = 0; mt < 4; ++mt) {
    const int c4 = mt * 16 + quad * 4;   // local channel group
    float s0 = 0.f, s1 = 0.f, s2 = 0.f, s3 = 0.f;
#pragma unroll
    for (int nt = 0; nt < 3; ++nt) {
      uint2 wv = *(const uint2*)(wt + ktab[nt] * TSE + c4);
      uint2 xv = *(const uint2*)(xt + irow[nt] * TSE + c4);
      float2 w01 = bfup(wv.x), w23 = bfup(wv.y);
      float2 x01 = bfup(xv.x), x23 = bfup(xv.y);
      s0 += acc[mt][nt][0] * (w01.x * x01.x);
      s1 += acc[mt][nt][1] * (w01.y * x01.y);
      s2 += acc[mt][nt][2] * (w23.x * x23.x);
      s3 += acc[mt][nt][3] * (w23.y * x23.y);
    }
    s0 = row16_sum(s0);
    s1 = row16_sum(s1);
    s2 = row16_sum(s2);
    s3 = row16_sum(s3);
    if (l16 == 15) {
      float* dst = ws + w * CHB + c4;
      if (FIRST) {
        *(float4*)dst = (float4){s0, s1, s2, s3};
      } else {
        float4 old = *(const float4*)dst;
        *(float4*)dst = (float4){old.x + s0, old.y + s1, old.z + s2, old.w + s3};
      }
    }
  }
}

__global__ __launch_bounds__(256, 4) void mace_main(
    const float* __restrict__ x, const float* __restrict__ y,
    const float* __restrict__ W1, const float* __restrict__ W2,
    const float* __restrict__ W3,
    const unsigned short* __restrict__ bt, float* __restrict__ out) {
  __shared__ __align__(16) char smem[SMEM_BYTES];
  const int t  = threadIdx.x;
  const int b  = blockIdx.y;
  const int ch0 = blockIdx.x * CHB;    // this block's channel range
  const int lane = t & 63, w = t >> 6;
  const int quad = lane >> 4, l16 = lane & 15;

  if (t < 128) {
    // ---- XX + XT build (threads 0..127; 2 threads per channel) ----
    const int c = t >> 1, half = t & 1;
    const float4* xs = (const float4*)(x + ((size_t)b * C_CH + ch0 + c) * L_DIM);
    float4 f0 = xs[0], f1 = xs[1], f2 = xs[2], f3 = xs[3];
    float xf[16] = {f0.x, f0.y, f0.z, f0.w, f1.x, f1.y, f1.z, f1.w,
                    f2.x, f2.y, f2.z, f2.w, f3.x, f3.y, f3.z, f3.w};
    // XT: half 0 writes rows 0..7, half 1 rows 8..15
    unsigned short* xtb = (unsigned short*)(smem + XT_OFF);
#pragma unroll
    for (int i = 0; i < 8; ++i) xtb[(half * 8 + i) * TSE + c] = f2bf(xf[half * 8 + i]);
    // XX[c, 0..135] = x_p*x_q bf16; slots 136..151 = x (corr-1 rows); 152..159 = 0
    unsigned* dst = (unsigned*)(smem + XX_OFF + c * KSB);
    float prev = 0.f;
    int idx = 0;
#pragma unroll
    for (int p = 0; p < 16; ++p) {
#pragma unroll
      for (int q = p; q < 16; ++q) {
        const bool mine = (idx < 68) == (half == 0);
        if (mine) {
          const float val = xf[p] * xf[q];
          if (idx & 1) dst[idx >> 1] = pack2(prev, val);
          else prev = val;
        }
        ++idx;
      }
    }
    if (half) {
#pragma unroll
      for (int j = 0; j < 8; ++j) dst[68 + j] = pack2(xf[2 * j], xf[2 * j + 1]);  // k 136..151 = x
#pragma unroll
      for (int j = 76; j < 80; ++j) dst[j] = 0u;                                  // k 152..159 = 0
    }
  } else {
    // ---- WT build (threads 128..255): wt[k][c], k: 0..22 w3, 23..26 w2, 27 w1, 28 zero ----
    const int tt = t - 128;
    unsigned short* xtb = (unsigned short*)(smem + XT_OFF);
    if (tt < CHB) xtb[16 * TSE + tt] = 0x3f80;   // ones row (bf16 1.0)
    float yv[E_EL];
#pragma unroll
    for (int e = 0; e < E_EL; ++e) yv[e] = y[(size_t)b * E_EL + e];  // wave-uniform -> s_load
    unsigned short* wtb = (unsigned short*)(smem + WT_OFF);
    for (int u = tt; u < 29 * 16; u += 128) {
      const int k = u >> 4, cg = (u & 15) * 4;
      float4 a = {0.f, 0.f, 0.f, 0.f};
      if (k < 23) {
#pragma unroll
        for (int e = 0; e < E_EL; ++e) {
          float4 wv = *(const float4*)(W3 + (e * NK3 + k) * C_CH + ch0 + cg);
          a.x += yv[e] * wv.x; a.y += yv[e] * wv.y; a.z += yv[e] * wv.z; a.w += yv[e] * wv.w;
        }
      } else if (k < 27) {
#pragma unroll
        for (int e = 0; e < E_EL; ++e) {
          float4 wv = *(const float4*)(W2 + (e * NK2 + (k - 23)) * C_CH + ch0 + cg);
          a.x += yv[e] * wv.x; a.y += yv[e] * wv.y; a.z += yv[e] * wv.z; a.w += yv[e] * wv.w;
        }
      } else if (k == 27) {
#pragma unroll
        for (int e = 0; e < E_EL; ++e) {
          float4 wv = *(const float4*)(W1 + e * C_CH + ch0 + cg);
          a.x += yv[e] * wv.x; a.y += yv[e] * wv.y; a.z += yv[e] * wv.z; a.w += yv[e] * wv.w;
        }
      }
      uint2 pw;
      pw.x = pack2(a.x, a.y);
      pw.y = pack2(a.z, a.w);
      *(uint2*)(wtb + k * TSE + cg) = pw;
    }
  }
  __syncthreads();
  // ---- two 48-column passes; wave partials accumulate in LDS ws ----
  float* ws = (float*)(smem + WS_OFF);
  do_pass<true >(smem, ws, bt, w * 96,      w, l16, quad);
  do_pass<false>(smem, ws, bt, w * 96 + 48, w, l16, quad);
  __syncthreads();
  // ---- final: sum 4 wave partials, plain coalesced store ----
  if (t < CHB) {
    float s = ws[t] + ws[CHB + t] + ws[2 * CHB + t] + ws[3 * CHB + t];
    out[(size_t)b * C_CH + ch0 + t] = s;
  }
}

extern "C" void kernel_launch(void* const* d_in, const int* in_sizes, int n_in,
                              void* d_out, int out_size, void* d_ws, size_t ws_size,
                              hipStream_t stream) {
  const float* x  = (const float*)d_in[0];
  const float* y  = (const float*)d_in[1];
  const float* U1 = (const float*)d_in[2];
  const float* U2 = (const float*)d_in[3];
  const float* U3 = (const float*)d_in[4];
  const float* W1 = (const float*)d_in[5];
  const float* W2 = (const float*)d_in[6];
  const float* W3 = (const float*)d_in[7];
  float* out = (float*)d_out;
  unsigned short* bt = (unsigned short*)d_ws;
  if (ws_size < (size_t)NCOL * KPAD * sizeof(unsigned short)) return;  // need 122,880 B scratch

  build_bt<<<dim3((NCOL * KPAD + 255) / 256), dim3(256), 0, stream>>>(U1, U2, U3, bt);
  mace_main<<<dim3(2, B_ATOMS), dim3(256), 0, stream>>>(x, y, W1, W2, W3, bt, out);
}

// Round 8
// 296.060 us; speedup vs baseline: 2.5304x; 1.0017x over previous
//
#include <hip/hip_runtime.h>
#include <hip/hip_bf16.h>
#include <stdint.h>

// ---- problem constants ----
#define B_ATOMS 8192
#define C_CH    128
#define CHB     64    // channels per block (c-half)
#define L_DIM   16
#define E_EL    10
#define NK3     23
#define NK2     4
#define NTRI    136   // 16*17/2 upper-triangle pairs
#define KPAD    160   // K padded to 32-multiple for 16x16x32 MFMA
#define NCOL    384   // 368 (i*23+k3) + 4 (k2) + 1 (U1 col 372) + 11 pad
#define KSB     336   // XX LDS k-stride BYTES (168 bf16; 84 dw = 20 mod 32 -> <=2-way b128)
#define TSE     72    // bf16 table row stride, elems (144 B = 36 dw)

// ---- LDS layout (bytes) ----
#define XX_OFF  0          // 64*336          = 21504
#define XT_OFF  21504      // bf16 [17][72]   =  2448 -> 23952  (row 16 = ones)
#define WT_OFF  23952      // bf16 [29][72]   =  4176 -> 28128  (row 28 = zero)
#define WS_OFF  28128      // f32 [4][64]     =  1024 -> 29152
#define SMEM_BYTES 29152   // 29.1 KB; VGPR<=128 -> 4 blocks/CU

typedef __attribute__((ext_vector_type(8))) short short8;
typedef __attribute__((ext_vector_type(4))) float f32x4;

struct TriLut { unsigned char p[NTRI]; unsigned char q[NTRI]; };
static constexpr TriLut make_lut() {
  TriLut t{};
  int idx = 0;
  for (int p = 0; p < 16; ++p)
    for (int q = p; q < 16; ++q) { t.p[idx] = (unsigned char)p; t.q[idx] = (unsigned char)q; ++idx; }
  return t;
}
__constant__ TriLut LUT = make_lut();   // runtime-indexed copy (build_bt)

// cheap bf16 packing: round-half-up (add 0x8000 to bits) — 3 VALU/pair, 2 VALU/single
__device__ __forceinline__ unsigned pack2_fast(float a, float b) {
  unsigned au = __float_as_uint(a) + 0x8000u;
  unsigned bu = __float_as_uint(b) + 0x8000u;
  return __builtin_amdgcn_perm(bu, au, 0x07060302u);  // [a_hi16 | b_hi16<<16]
}
__device__ __forceinline__ unsigned short f2bf_fast(float f) {
  return (unsigned short)((__float_as_uint(f) + 0x8000u) >> 16);
}
__device__ __forceinline__ unsigned short f2bf(float f) {   // RNE (setup kernel only)
  union { float f; unsigned u; } v; v.f = f;
  unsigned r = v.u + 0x7fffu + ((v.u >> 16) & 1u);
  return (unsigned short)(r >> 16);
}
__device__ __forceinline__ float2 bfup(unsigned u) {   // unpack bf16 pair -> 2 floats
  float2 r;
  r.x = __uint_as_float(u << 16);
  r.y = __uint_as_float(u & 0xffff0000u);
  return r;
}
// 16-lane (DPP row) reduce; after shr 1,2,4,8 lane15 holds the row sum.
template <int CTRL>
__device__ __forceinline__ float dpp_add(float s) {
  int v = __builtin_amdgcn_update_dpp(0, __float_as_int(s), CTRL, 0xf, 0xf, true);
  return s + __int_as_float(v);
}
__device__ __forceinline__ float row16_sum(float s) {
  s = dpp_add<0x111>(s);
  s = dpp_add<0x112>(s);
  s = dpp_add<0x114>(s);
  s = dpp_add<0x118>(s);
  return s;
}

// ---- setup: pack symmetrized B' [n=384][k=160] bf16 into workspace ----
__global__ void build_bt(const float* __restrict__ U1, const float* __restrict__ U2,
                         const float* __restrict__ U3, unsigned short* __restrict__ bt) {
  int gid = blockIdx.x * 256 + threadIdx.x;
  if (gid >= NCOL * KPAD) return;
  int n  = gid / KPAD;
  int kk = gid - n * KPAD;
  float val = 0.f;
  if (kk < NTRI && n < 372) {
    int p = LUT.p[kk], q = LUT.q[kk];
    if (n < 368) {
      int i = n / NK3, k3 = n - i * NK3;
      val = U3[((p * 16 + q) * 16 + i) * NK3 + k3];
      if (p != q) val += U3[((q * 16 + p) * 16 + i) * NK3 + k3];
    } else {
      int k2 = n - 368;
      val = U2[(p * 16 + q) * NK2 + k2];
      if (p != q) val += U2[(q * 16 + p) * NK2 + k2];
    }
  } else if (n == 372 && kk >= 136 && kk < 152) {
    val = U1[kk - 136];   // pairs with XX k-slots 136..151 = x  ->  V[c,372] = sum_p U1_p x_p
  }
  bt[gid] = f2bf(val);
}

// XX pair-slots [20*W, 20*W+20) for one channel row; compile-time (p,q) decode.
template <int W>
__device__ __forceinline__ void xx_slots(unsigned* __restrict__ dst, const float* __restrict__ xf) {
  constexpr TriLut CL = make_lut();
#pragma unroll
  for (int j = W * 20; j < W * 20 + 20; ++j) {
    if (j < 68) {
      const float v0 = xf[CL.p[2 * j]] * xf[CL.q[2 * j]];
      const float v1 = xf[CL.p[2 * j + 1]] * xf[CL.q[2 * j + 1]];
      dst[j] = pack2_fast(v0, v1);
    } else if (j < 76) {
      const int i0 = (j - 68) * 2;            // k-slots 136..151 = x (corr-1 rows)
      dst[j] = pack2_fast(xf[i0], xf[i0 + 1]);
    } else {
      dst[j] = 0u;                            // k 152..159 = 0
    }
  }
}

// One 48-column pass: B' frags streamed from global per ks (1-deep prefetch),
// GEMM (64 rows x 48 cols), weighted epilogue, DPP reduce, wave partials in ws.
template <bool FIRST>
__device__ __forceinline__ void do_pass(const char* __restrict__ smem, float* __restrict__ ws,
                                        const unsigned short* __restrict__ bt,
                                        int nbase, int w, int l16, int quad) {
  const unsigned short* bp[3];
#pragma unroll
  for (int nt = 0; nt < 3; ++nt)
    bp[nt] = bt + (size_t)(nbase + nt * 16 + l16) * KPAD + quad * 8;

  short8 bcur[3], bnxt[3];
#pragma unroll
  for (int nt = 0; nt < 3; ++nt) bcur[nt] = *(const short8*)(bp[nt]);

  f32x4 acc[4][3];
#pragma unroll
  for (int mt = 0; mt < 4; ++mt)
#pragma unroll
    for (int nt = 0; nt < 3; ++nt) acc[mt][nt] = (f32x4){0.f, 0.f, 0.f, 0.f};

#pragma unroll
  for (int ks = 0; ks < 5; ++ks) {
    if (ks < 4) {
#pragma unroll
      for (int nt = 0; nt < 3; ++nt) bnxt[nt] = *(const short8*)(bp[nt] + (ks + 1) * 32);
    }
    short8 af[4];
#pragma unroll
    for (int mt = 0; mt < 4; ++mt)
      af[mt] = *(const short8*)(smem + XX_OFF + (mt * 16 + l16) * KSB + ks * 64 + quad * 16);
#pragma unroll
    for (int nt = 0; nt < 3; ++nt)
#pragma unroll
      for (int mt = 0; mt < 4; ++mt)
        acc[mt][nt] = __builtin_amdgcn_mfma_f32_16x16x32_bf16(af[mt], bcur[nt], acc[mt][nt], 0, 0, 0);
#pragma unroll
    for (int nt = 0; nt < 3; ++nt) bcur[nt] = bnxt[nt];
  }

  // epilogue decode: irow = n/23 (16 = ones row for n>=368); ktab clamped to zero-row 28
  int ktab[3], irow[3];
#pragma unroll
  for (int nt = 0; nt < 3; ++nt) {
    const int n = nbase + nt * 16 + l16;
    const int i = n / NK3;
    irow[nt] = i;
    ktab[nt] = (n < 368) ? (n - i * NK3) : min(n - 345, 28);
  }
  const unsigned short* xt = (const unsigned short*)(smem + XT_OFF);
  const unsigned short* wt = (const unsigned short*)(smem + WT_OFF);
#pragma unroll
  for (int mt = 0; mt < 4; ++mt) {
    const int c4 = mt * 16 + quad * 4;   // local channel group
    float s0 = 0.f, s1 = 0.f, s2 = 0.f, s3 = 0.f;
#pragma unroll
    for (int nt = 0; nt < 3; ++nt) {
      uint2 wv = *(const uint2*)(wt + ktab[nt] * TSE + c4);
      uint2 xv = *(const uint2*)(xt + irow[nt] * TSE + c4);
      float2 w01 = bfup(wv.x), w23 = bfup(wv.y);
      float2 x01 = bfup(xv.x), x23 = bfup(xv.y);
      s0 += acc[mt][nt][0] * (w01.x * x01.x);
      s1 += acc[mt][nt][1] * (w01.y * x01.y);
      s2 += acc[mt][nt][2] * (w23.x * x23.x);
      s3 += acc[mt][nt][3] * (w23.y * x23.y);
    }
    s0 = row16_sum(s0);
    s1 = row16_sum(s1);
    s2 = row16_sum(s2);
    s3 = row16_sum(s3);
    if (l16 == 15) {
      float* dst = ws + w * CHB + c4;
      if (FIRST) {
        *(float4*)dst = (float4){s0, s1, s2, s3};
      } else {
        float4 old = *(const float4*)dst;
        *(float4*)dst = (float4){old.x + s0, old.y + s1, old.z + s2, old.w + s3};
      }
    }
  }
}

__global__ __launch_bounds__(256, 4) void mace_main(
    const float* __restrict__ x, const float* __restrict__ y,
    const float* __restrict__ W1, const float* __restrict__ W2,
    const float* __restrict__ W3,
    const unsigned short* __restrict__ bt, float* __restrict__ out) {
  __shared__ __align__(16) char smem[SMEM_BYTES];
  const int t  = threadIdx.x;
  const int b  = blockIdx.y;
  const int ch0 = blockIdx.x * CHB;    // this block's channel range
  const int lane = t & 63, w = t >> 6;
  const int quad = lane >> 4, l16 = lane & 15;

  // ---- staging: lane = channel; wave w owns XX pair-slots [20w, 20w+20) ----
  {
    const float4* xs = (const float4*)(x + ((size_t)b * C_CH + ch0 + lane) * L_DIM);
    float4 f0 = xs[0], f1 = xs[1], f2 = xs[2], f3 = xs[3];
    float xf[16] = {f0.x, f0.y, f0.z, f0.w, f1.x, f1.y, f1.z, f1.w,
                    f2.x, f2.y, f2.z, f2.w, f3.x, f3.y, f3.z, f3.w};
    unsigned* dst = (unsigned*)(smem + XX_OFF + lane * KSB);
    const int wu = __builtin_amdgcn_readfirstlane(w);   // wave-uniform -> scalar branch
    switch (wu) {
      case 0: xx_slots<0>(dst, xf); break;
      case 1: xx_slots<1>(dst, xf); break;
      case 2: xx_slots<2>(dst, xf); break;
      default: xx_slots<3>(dst, xf); break;
    }
    if (wu == 1) {   // XT build: rows 0..15 + ones row, lane = channel
      unsigned short* xtb = (unsigned short*)(smem + XT_OFF);
#pragma unroll
      for (int i = 0; i < 16; ++i) xtb[i * TSE + lane] = f2bf_fast(xf[i]);
      xtb[16 * TSE + lane] = 0x3f80;   // bf16 1.0
    }
  }
  // ---- WT build (all 256 threads): wt[k][c], k: 0..22 w3, 23..26 w2, 27 w1, 28 zero ----
  {
    float yv[E_EL];
#pragma unroll
    for (int e = 0; e < E_EL; ++e) yv[e] = y[(size_t)b * E_EL + e];  // wave-uniform -> s_load
    unsigned short* wtb = (unsigned short*)(smem + WT_OFF);
    for (int u = t; u < 29 * 16; u += 256) {
      const int k = u >> 4, cg = (u & 15) * 4;
      float4 a = {0.f, 0.f, 0.f, 0.f};
      if (k < 23) {
#pragma unroll
        for (int e = 0; e < E_EL; ++e) {
          float4 wv = *(const float4*)(W3 + (e * NK3 + k) * C_CH + ch0 + cg);
          a.x += yv[e] * wv.x; a.y += yv[e] * wv.y; a.z += yv[e] * wv.z; a.w += yv[e] * wv.w;
        }
      } else if (k < 27) {
#pragma unroll
        for (int e = 0; e < E_EL; ++e) {
          float4 wv = *(const float4*)(W2 + (e * NK2 + (k - 23)) * C_CH + ch0 + cg);
          a.x += yv[e] * wv.x; a.y += yv[e] * wv.y; a.z += yv[e] * wv.z; a.w += yv[e] * wv.w;
        }
      } else if (k == 27) {
#pragma unroll
        for (int e = 0; e < E_EL; ++e) {
          float4 wv = *(const float4*)(W1 + e * C_CH + ch0 + cg);
          a.x += yv[e] * wv.x; a.y += yv[e] * wv.y; a.z += yv[e] * wv.z; a.w += yv[e] * wv.w;
        }
      }
      uint2 pw;
      pw.x = pack2_fast(a.x, a.y);
      pw.y = pack2_fast(a.z, a.w);
      *(uint2*)(wtb + k * TSE + cg) = pw;
    }
  }
  __syncthreads();
  // ---- two 48-column passes; wave partials accumulate in LDS ws ----
  float* ws = (float*)(smem + WS_OFF);
  do_pass<true >(smem, ws, bt, w * 96,      w, l16, quad);
  do_pass<false>(smem, ws, bt, w * 96 + 48, w, l16, quad);
  __syncthreads();
  // ---- final: sum 4 wave partials, plain coalesced store ----
  if (t < CHB) {
    float s = ws[t] + ws[CHB + t] + ws[2 * CHB + t] + ws[3 * CHB + t];
    out[(size_t)b * C_CH + ch0 + t] = s;
  }
}

extern "C" void kernel_launch(void* const* d_in, const int* in_sizes, int n_in,
                              void* d_out, int out_size, void* d_ws, size_t ws_size,
                              hipStream_t stream) {
  const float* x  = (const float*)d_in[0];
  const float* y  = (const float*)d_in[1];
  const float* U1 = (const float*)d_in[2];
  const float* U2 = (const float*)d_in[3];
  const float* U3 = (const float*)d_in[4];
  const float* W1 = (const float*)d_in[5];
  const float* W2 = (const float*)d_in[6];
  const float* W3 = (const float*)d_in[7];
  float* out = (float*)d_out;
  unsigned short* bt = (unsigned short*)d_ws;
  if (ws_size < (size_t)NCOL * KPAD * sizeof(unsigned short)) return;  // need 122,880 B scratch

  build_bt<<<dim3((NCOL * KPAD + 255) / 256), dim3(256), 0, stream>>>(U1, U2, U3, bt);
  mace_main<<<dim3(2, B_ATOMS), dim3(256), 0, stream>>>(x, y, W1, W2, W3, bt, out);
}